// Round 6
// baseline (1071.451 us; speedup 1.0000x reference)
//
#include <hip/hip_runtime.h>
#include <hip/hip_bf16.h>
#include <stdint.h>

typedef float  f32x4  __attribute__((ext_vector_type(4)));
typedef short  bf16x8 __attribute__((ext_vector_type(8)));
typedef unsigned short u16x8 __attribute__((ext_vector_type(8)));

#define MFMA16(a, b, c) __builtin_amdgcn_mfma_f32_16x16x32_bf16((a), (b), (c), 0, 0, 0)

__device__ __forceinline__ void gload16(const void* g, void* l) {
  __builtin_amdgcn_global_load_lds((const __attribute__((address_space(1))) void*)g,
                                   (__attribute__((address_space(3))) void*)l,
                                   16, 0, 0);
}

__device__ __forceinline__ unsigned short bf16bits(float f) {
  __hip_bfloat16 h = __float2bfloat16(f);
  return *(unsigned short*)&h;
}

__device__ __forceinline__ float bf2f(unsigned short u) {
  unsigned int x = ((unsigned int)u) << 16;
  return *(float*)&x;
}

// ---------------- fp32 -> bf16 cast, 4 elems/thread ----------------
__global__ void cast_kernel(const float* __restrict__ s, __hip_bfloat16* __restrict__ d, int n4) {
  int i = blockIdx.x * blockDim.x + threadIdx.x;
  if (i < n4) {
    float4 v = ((const float4*)s)[i];
    ushort4 u;
    u.x = bf16bits(v.x); u.y = bf16bits(v.y); u.z = bf16bits(v.z); u.w = bf16bits(v.w);
    ((ushort4*)d)[i] = u;
  }
}

// ---------------- GEMM1: qkv = xb @ wqkvb^T + b_qkv; scatter to Q,K,Vt (bf16) ----------------
__global__ __launch_bounds__(256) void gemm_qkv_kernel(
    const __hip_bfloat16* __restrict__ A,
    const __hip_bfloat16* __restrict__ B,
    const float* __restrict__ bias,
    __hip_bfloat16* __restrict__ Qo,
    __hip_bfloat16* __restrict__ Ko,
    __hip_bfloat16* __restrict__ Vt) {
  const int K = 1024;
  __shared__ __align__(16) __hip_bfloat16 As[128 * 32];
  __shared__ __align__(16) __hip_bfloat16 Bs[128 * 32];
  const int t = threadIdx.x;
  const int lane = t & 63, wv = t >> 6;
  const int wm = (wv >> 1) * 64, wn = (wv & 1) * 64;
  const int lr = lane & 15, lq = lane >> 4;
  const int m0 = blockIdx.y * 128, n0 = blockIdx.x * 128;

  f32x4 acc[4][4] = {};

  const int arow = t >> 2;
  const int acol = (t & 3) * 8;
  const __hip_bfloat16* Ag = A + (long)(m0 + arow) * K + acol;
  const __hip_bfloat16* Bg = B + (long)(n0 + arow) * K + acol;
  __hip_bfloat16* Asl = As + t * 8;
  __hip_bfloat16* Bsl = Bs + t * 8;

  for (int kk = 0; kk < K; kk += 32) {
    gload16(Ag + kk, Asl);
    gload16(Ag + kk + 64 * K, Asl + 2048);
    gload16(Bg + kk, Bsl);
    gload16(Bg + kk + 64 * K, Bsl + 2048);
    __syncthreads();
    bf16x8 af[4], bf[4];
#pragma unroll
    for (int i = 0; i < 4; ++i)
      af[i] = *(const bf16x8*)&As[(wm + i * 16 + lr) * 32 + lq * 8];
#pragma unroll
    for (int j = 0; j < 4; ++j)
      bf[j] = *(const bf16x8*)&Bs[(wn + j * 16 + lr) * 32 + lq * 8];
#pragma unroll
    for (int i = 0; i < 4; ++i)
#pragma unroll
      for (int j = 0; j < 4; ++j)
        acc[i][j] = MFMA16(af[i], bf[j], acc[i][j]);
    __syncthreads();
  }

#pragma unroll
  for (int i = 0; i < 4; ++i) {
#pragma unroll
    for (int j = 0; j < 4; ++j) {
      int col = n0 + wn + j * 16 + lr;
      int tsel = col >> 10, rem = col & 1023;
      int h = rem >> 6, d = rem & 63;
      float bs = bias[col];
      int rowb = m0 + wm + i * 16 + lq * 4;
#pragma unroll
      for (int r = 0; r < 4; ++r) {
        int m = rowb + r;
        int b = m >> 11, sdx = m & 2047;
        __hip_bfloat16 v = __float2bfloat16(acc[i][j][r] + bs);
        long bh = (long)(b * 16 + h);
        if (tsel == 0)       Qo[(bh * 2048 + sdx) * 64 + d] = v;
        else if (tsel == 1)  Ko[(bh * 2048 + sdx) * 64 + d] = v;
        else                 Vt[(bh * 64 + d) * 2048 + sdx] = v;
      }
    }
  }
}

// ---------------- fused attention ----------------
// 1-D grid 1024; combo = blockIdx&7 -> (b,chunk): one K/V working set per XCD.
// LDS = P only (32 KB, XOR-granule swizzle) -> 3 blocks/CU (VGPR-bound at
// launch_bounds(256,3): need >=128 live f32 for s[16]+ctx, cap ~170).
// Q frags re-loaded from global each iter (same addrs -> L1/L2 hot, pipelined
// with K batch). K loads batched in halves of 8 heads (64 VGPRs/batch) so the
// allocator keeps them in flight (R5: full 128-reg batch got re-serialized).
__global__ __launch_bounds__(256, 3) void attn_kernel(
    const __hip_bfloat16* __restrict__ Q,
    const __hip_bfloat16* __restrict__ K,
    const __hip_bfloat16* __restrict__ Vt,
    __hip_bfloat16* __restrict__ part) {
  __shared__ __align__(16) __hip_bfloat16 P[16 * 16 * 64];   // 32 KB
  const int t = threadIdx.x, lane = t & 63, wv = t >> 6;
  const int lr = lane & 15, lq = lane >> 4;
  const int combo = blockIdx.x & 7;
  const int b = combo & 1, chunk = combo >> 1;
  const int q0 = (blockIdx.x >> 3) * 16;
  const int k0 = chunk * 512;
  const float c = 0.03125f * 1.44269504f;  // (1/sqrt(E)) * log2(e), E=1024
  const long bh16 = (long)(b * 16);

  f32x4 ctx[4][4] = {};

  const __hip_bfloat16* Qbase = Q + (bh16 * 2048 + q0 + lr) * 64 + lq * 8;

  for (int kk = k0; kk < k0 + 512; kk += 64) {
    f32x4 s[16];
    // two half-batches of 8 heads: 16 b128 K-frags (64 VGPRs) in flight each
#pragma unroll
    for (int half = 0; half < 2; ++half) {
      bf16x8 kfa[8], kfb[8];
#pragma unroll
      for (int hh = 0; hh < 8; ++hh) {
        const int h = half * 8 + hh;
        const __hip_bfloat16* kp =
            K + ((bh16 + h) * 2048 + kk + wv * 16 + lr) * 64 + lq * 8;
        kfa[hh] = *(const bf16x8*)kp;
        kfb[hh] = *(const bf16x8*)(kp + 32);
      }
#pragma unroll
      for (int hh = 0; hh < 8; ++hh) {
        const int h = half * 8 + hh;
        const __hip_bfloat16* qp = Qbase + (long)h * (2048 * 64);
        bf16x8 qa = *(const bf16x8*)qp;
        bf16x8 qb = *(const bf16x8*)(qp + 32);
        f32x4 a = {};
        a = MFMA16(qa, kfa[hh], a);
        a = MFMA16(qb, kfb[hh], a);
        s[h] = a;
      }
    }
    // head-axis softmax per lane (no max-sub: |score| small at scale 1/32)
    f32x4 sum = {0.f, 0.f, 0.f, 0.f};
#pragma unroll
    for (int h = 0; h < 16; ++h) {
#pragma unroll
      for (int r = 0; r < 4; ++r) s[h][r] = __builtin_amdgcn_exp2f(s[h][r] * c);
      sum += s[h];
    }
    f32x4 inv;
#pragma unroll
    for (int r = 0; r < 4; ++r) inv[r] = __builtin_amdgcn_rcpf(sum[r]);
    // P[h*16+q][k] swizzled; this wave's k-columns = wv*16 + lr
    const int gcol = (wv * 16 + lr) >> 3, coff = lr & 7;
#pragma unroll
    for (int h = 0; h < 16; ++h)
#pragma unroll
      for (int r = 0; r < 4; ++r) {
        int row = h * 16 + lq * 4 + r;
        P[row * 64 + ((gcol ^ (row & 7)) << 3) + coff] = __float2bfloat16(s[h][r] * inv[r]);
      }
    __syncthreads();
    // ---- PV for this wave's 4 heads, V frags batched per head ----
#pragma unroll
    for (int hh = 0; hh < 4; ++hh) {
      const int h = wv * 4 + hh;
      const __hip_bfloat16* vb = Vt + ((bh16 + h) * 64 + lr) * 2048 + kk + lq * 8;
      bf16x8 vf[8];
#pragma unroll
      for (int dt = 0; dt < 4; ++dt) {
        vf[dt * 2]     = *(const bf16x8*)(vb + (long)dt * 16 * 2048);
        vf[dt * 2 + 1] = *(const bf16x8*)(vb + (long)dt * 16 * 2048 + 32);
      }
      const int prow = h * 16 + lr;
      bf16x8 pf0 = *(const bf16x8*)&P[prow * 64 + ((lq ^ (lr & 7)) << 3)];
      bf16x8 pf1 = *(const bf16x8*)&P[prow * 64 + (((lq + 4) ^ (lr & 7)) << 3)];
#pragma unroll
      for (int dt = 0; dt < 4; ++dt) {
        ctx[hh][dt] = MFMA16(pf0, vf[dt * 2], ctx[hh][dt]);
        ctx[hh][dt] = MFMA16(pf1, vf[dt * 2 + 1], ctx[hh][dt]);
      }
    }
    __syncthreads();
  }

  // ---- epilogue: ctx -> LDS (reuse P, same swizzle) -> coalesced wide store ----
  unsigned short* Pc = (unsigned short*)P;
#pragma unroll
  for (int hh = 0; hh < 4; ++hh) {
    int h = wv * 4 + hh;
#pragma unroll
    for (int dt = 0; dt < 4; ++dt) {
      int g = dt * 2 + (lr >> 3), off = lr & 7;
#pragma unroll
      for (int r = 0; r < 4; ++r) {
        int row = h * 16 + lq * 4 + r;
        Pc[row * 64 + ((g ^ (row & 7)) << 3) + off] = bf16bits(ctx[hh][dt][r]);
      }
    }
  }
  __syncthreads();
  // part[chunk][b][q0..q0+15][h*64+d]: contiguous 32 KB per CTA.
  unsigned short* gbase = (unsigned short*)part + ((long)(chunk * 4096 + b * 2048 + q0)) * 1024;
#pragma unroll
  for (int j = 0; j < 8; ++j) {
    int gf = (j * 256 + t) * 8;            // flat over [16q][16h][64d]
    int q = gf >> 10, hd = gf & 1023;
    int h = hd >> 6, d = hd & 63;
    int row = h * 16 + q, gd = (d >> 3) & 7;
    u16x8 v = *(const u16x8*)&Pc[row * 64 + ((gd ^ (row & 7)) << 3)];
    *(u16x8*)&gbase[gf] = v;
  }
}

// ---------------- reduce 4 bf16 chunk partials + cast to bf16 ----------------
__global__ void reduce_cast_kernel(const unsigned short* __restrict__ part,
                                   __hip_bfloat16* __restrict__ dst) {
  int i = blockIdx.x * blockDim.x + threadIdx.x;  // 1M threads, 4 elems each
  const long S4 = (long)4096 * 1024 / 4;          // ushort4 units per chunk
  const ushort4* p = (const ushort4*)part;
  float sx = 0.f, sy = 0.f, sz = 0.f, sw = 0.f;
#pragma unroll
  for (int c = 0; c < 4; ++c) {
    ushort4 v = p[i + c * S4];
    sx += bf2f(v.x); sy += bf2f(v.y); sz += bf2f(v.z); sw += bf2f(v.w);
  }
  ushort4 u;
  u.x = bf16bits(sx); u.y = bf16bits(sy); u.z = bf16bits(sz); u.w = bf16bits(sw);
  ((ushort4*)dst)[i] = u;
}

// ---------------- GEMM2: out = ctxb @ woutb^T + b_out (fp32 out) ----------------
__global__ __launch_bounds__(256) void gemm_out_kernel(
    const __hip_bfloat16* __restrict__ A,   // [4096][1024]
    const __hip_bfloat16* __restrict__ B,   // [1024][1024]
    const float* __restrict__ bias,
    float* __restrict__ out) {
  const int K = 1024;
  __shared__ __align__(16) __hip_bfloat16 As[128 * 32];
  __shared__ __align__(16) __hip_bfloat16 Bs[128 * 32];
  const int t = threadIdx.x;
  const int lane = t & 63, wv = t >> 6;
  const int wm = (wv >> 1) * 64, wn = (wv & 1) * 64;
  const int lr = lane & 15, lq = lane >> 4;
  const int m0 = blockIdx.y * 128, n0 = blockIdx.x * 128;

  f32x4 acc[4][4] = {};

  const int arow = t >> 2;
  const int acol = (t & 3) * 8;
  const __hip_bfloat16* Ag = A + (long)(m0 + arow) * K + acol;
  const __hip_bfloat16* Bg = B + (long)(n0 + arow) * K + acol;
  __hip_bfloat16* Asl = As + t * 8;
  __hip_bfloat16* Bsl = Bs + t * 8;

  for (int kk = 0; kk < K; kk += 32) {
    gload16(Ag + kk, Asl);
    gload16(Ag + kk + 64 * K, Asl + 2048);
    gload16(Bg + kk, Bsl);
    gload16(Bg + kk + 64 * K, Bsl + 2048);
    __syncthreads();
    bf16x8 af[4], bf[4];
#pragma unroll
    for (int i = 0; i < 4; ++i)
      af[i] = *(const bf16x8*)&As[(wm + i * 16 + lr) * 32 + lq * 8];
#pragma unroll
    for (int j = 0; j < 4; ++j)
      bf[j] = *(const bf16x8*)&Bs[(wn + j * 16 + lr) * 32 + lq * 8];
#pragma unroll
    for (int i = 0; i < 4; ++i)
#pragma unroll
      for (int j = 0; j < 4; ++j)
        acc[i][j] = MFMA16(af[i], bf[j], acc[i][j]);
    __syncthreads();
  }

#pragma unroll
  for (int i = 0; i < 4; ++i) {
#pragma unroll
    for (int j = 0; j < 4; ++j) {
      int col = n0 + wn + j * 16 + lr;
      float bs = bias[col];
      int rowb = m0 + wm + i * 16 + lq * 4;
#pragma unroll
      for (int r = 0; r < 4; ++r) {
        out[(long)(rowb + r) * 1024 + col] = acc[i][j][r] + bs;
      }
    }
  }
}

extern "C" void kernel_launch(void* const* d_in, const int* in_sizes, int n_in,
                              void* d_out, int out_size, void* d_ws, size_t ws_size,
                              hipStream_t stream) {
  const float* x     = (const float*)d_in[0];
  const float* w_qkv = (const float*)d_in[1];
  const float* b_qkv = (const float*)d_in[2];
  const float* w_out = (const float*)d_in[3];
  const float* b_out = (const float*)d_in[4];
  float* out = (float*)d_out;
  char* ws = (char*)d_ws;

  // workspace layout (80 MB total)
  __hip_bfloat16* xb    = (__hip_bfloat16*)(ws);                       // 8 MB
  __hip_bfloat16* wqkvb = (__hip_bfloat16*)(ws + (8ul << 20));         // 6 MB
  __hip_bfloat16* woutb = (__hip_bfloat16*)(ws + (14ul << 20));        // 2 MB
  __hip_bfloat16* Qb    = (__hip_bfloat16*)(ws + (16ul << 20));        // 8 MB
  __hip_bfloat16* Kb    = (__hip_bfloat16*)(ws + (24ul << 20));        // 8 MB
  __hip_bfloat16* Vtb   = (__hip_bfloat16*)(ws + (32ul << 20));        // 8 MB
  __hip_bfloat16* partb = (__hip_bfloat16*)(ws + (40ul << 20));        // 32 MB (4 bf16 chunks)
  __hip_bfloat16* ctxb  = (__hip_bfloat16*)(ws + (72ul << 20));        // 8 MB

  cast_kernel<<<4096, 256, 0, stream>>>(x, xb, 4194304 / 4);
  cast_kernel<<<3072, 256, 0, stream>>>(w_qkv, wqkvb, 3145728 / 4);
  cast_kernel<<<1024, 256, 0, stream>>>(w_out, woutb, 1048576 / 4);
  gemm_qkv_kernel<<<dim3(24, 32), 256, 0, stream>>>(xb, wqkvb, b_qkv, Qb, Kb, Vtb);
  attn_kernel<<<1024, 256, 0, stream>>>(Qb, Kb, Vtb, partb);
  reduce_cast_kernel<<<4096, 256, 0, stream>>>((const unsigned short*)partb, ctxb);
  gemm_out_kernel<<<dim3(8, 32), 256, 0, stream>>>(ctxb, woutb, b_out, out);
}

// Round 7
// 589.089 us; speedup vs baseline: 1.8188x; 1.8188x over previous
//
#include <hip/hip_runtime.h>
#include <hip/hip_bf16.h>
#include <stdint.h>

typedef float  f32x4  __attribute__((ext_vector_type(4)));
typedef short  bf16x8 __attribute__((ext_vector_type(8)));
typedef unsigned short u16x8 __attribute__((ext_vector_type(8)));

#define MFMA16(a, b, c) __builtin_amdgcn_mfma_f32_16x16x32_bf16((a), (b), (c), 0, 0, 0)

__device__ __forceinline__ void gload16(const void* g, void* l) {
  __builtin_amdgcn_global_load_lds((const __attribute__((address_space(1))) void*)g,
                                   (__attribute__((address_space(3))) void*)l,
                                   16, 0, 0);
}

__device__ __forceinline__ unsigned short bf16bits(float f) {
  __hip_bfloat16 h = __float2bfloat16(f);
  return *(unsigned short*)&h;
}

__device__ __forceinline__ float bf2f(unsigned short u) {
  unsigned int x = ((unsigned int)u) << 16;
  return *(float*)&x;
}

// ---------------- fp32 -> bf16 cast, 4 elems/thread ----------------
__global__ void cast_kernel(const float* __restrict__ s, __hip_bfloat16* __restrict__ d, int n4) {
  int i = blockIdx.x * blockDim.x + threadIdx.x;
  if (i < n4) {
    float4 v = ((const float4*)s)[i];
    ushort4 u;
    u.x = bf16bits(v.x); u.y = bf16bits(v.y); u.z = bf16bits(v.z); u.w = bf16bits(v.w);
    ((ushort4*)d)[i] = u;
  }
}

// ---------------- GEMM1: qkv = xb @ wqkvb^T + b_qkv ----------------
// Epilogue scatters Q,K,V directly into MFMA-FRAGMENT order so attn loads are
// lane-contiguous (R6 analysis: row-strided fragment loads were ~16 tx/instr).
// Fragment tile = 512 elems, lane-major: elem(lane, j).
//  Q/K (A/B op of QK^T, 16 s-rows x 32 d): idx = bh*131072 + (s>>4)*1024
//      + (d>>5)*512 + ((s&15) + ((d>>3)&3)*16)*8 + (d&7)
//  V (B op of PV, 16 d x 32 keys):        idx = bh*131072 + (s>>5)*2048
//      + (d>>4)*512 + ((d&15) + ((s>>3)&3)*16)*8 + (s&7)
__global__ __launch_bounds__(256) void gemm_qkv_kernel(
    const __hip_bfloat16* __restrict__ A,
    const __hip_bfloat16* __restrict__ B,
    const float* __restrict__ bias,
    __hip_bfloat16* __restrict__ Qf,
    __hip_bfloat16* __restrict__ Kf,
    __hip_bfloat16* __restrict__ Vf) {
  const int K = 1024;
  __shared__ __align__(16) __hip_bfloat16 As[128 * 32];
  __shared__ __align__(16) __hip_bfloat16 Bs[128 * 32];
  const int t = threadIdx.x;
  const int lane = t & 63, wv = t >> 6;
  const int wm = (wv >> 1) * 64, wn = (wv & 1) * 64;
  const int lr = lane & 15, lq = lane >> 4;
  const int m0 = blockIdx.y * 128, n0 = blockIdx.x * 128;

  f32x4 acc[4][4] = {};

  const int arow = t >> 2;
  const int acol = (t & 3) * 8;
  const __hip_bfloat16* Ag = A + (long)(m0 + arow) * K + acol;
  const __hip_bfloat16* Bg = B + (long)(n0 + arow) * K + acol;
  __hip_bfloat16* Asl = As + t * 8;
  __hip_bfloat16* Bsl = Bs + t * 8;

  for (int kk = 0; kk < K; kk += 32) {
    gload16(Ag + kk, Asl);
    gload16(Ag + kk + 64 * K, Asl + 2048);
    gload16(Bg + kk, Bsl);
    gload16(Bg + kk + 64 * K, Bsl + 2048);
    __syncthreads();
    bf16x8 af[4], bf[4];
#pragma unroll
    for (int i = 0; i < 4; ++i)
      af[i] = *(const bf16x8*)&As[(wm + i * 16 + lr) * 32 + lq * 8];
#pragma unroll
    for (int j = 0; j < 4; ++j)
      bf[j] = *(const bf16x8*)&Bs[(wn + j * 16 + lr) * 32 + lq * 8];
#pragma unroll
    for (int i = 0; i < 4; ++i)
#pragma unroll
      for (int j = 0; j < 4; ++j)
        acc[i][j] = MFMA16(af[i], bf[j], acc[i][j]);
    __syncthreads();
  }

#pragma unroll
  for (int i = 0; i < 4; ++i) {
#pragma unroll
    for (int j = 0; j < 4; ++j) {
      int col = n0 + wn + j * 16 + lr;
      int tsel = col >> 10, rem = col & 1023;
      int h = rem >> 6, d = rem & 63;
      float bs = bias[col];
      int rowb = m0 + wm + i * 16 + lq * 4;
#pragma unroll
      for (int r = 0; r < 4; ++r) {
        int m = rowb + r;
        int b = m >> 11, sdx = m & 2047;
        __hip_bfloat16 v = __float2bfloat16(acc[i][j][r] + bs);
        long bh = (long)(b * 16 + h) * 131072;
        if (tsel == 2) {
          Vf[bh + (long)(sdx >> 5) * 2048 + (d >> 4) * 512 +
             ((d & 15) + (((sdx >> 3) & 3) << 4)) * 8 + (sdx & 7)] = v;
        } else {
          long idx = bh + (long)(sdx >> 4) * 1024 + (d >> 5) * 512 +
                     ((sdx & 15) + (((d >> 3) & 3) << 4)) * 8 + (d & 7);
          if (tsel == 0) Qf[idx] = v; else Kf[idx] = v;
        }
      }
    }
  }
}

// ---------------- fused attention ----------------
// 1-D grid 1024; combo = blockIdx&7 -> (b,chunk): one K/V working set per XCD.
// Q/K/V pre-swizzled to fragment order: every load is base + lane*16B (fully
// coalesced). LDS = P only (32 KB, XOR-granule swizzle). launch_bounds(256,2):
// the R5 spill-free point (R6's (256,3) cap 170 spilled: 84 VGPR + 1.4 GB scratch).
// K loads grouped 4 heads (8 frags = 32 transient VGPRs) so allocator keeps them.
__global__ __launch_bounds__(256, 2) void attn_kernel(
    const __hip_bfloat16* __restrict__ Qf,
    const __hip_bfloat16* __restrict__ Kf,
    const __hip_bfloat16* __restrict__ Vf,
    __hip_bfloat16* __restrict__ part) {
  __shared__ __align__(16) __hip_bfloat16 P[16 * 16 * 64];   // 32 KB
  const int t = threadIdx.x, lane = t & 63, wv = t >> 6;
  const int lr = lane & 15, lq = lane >> 4;
  const int combo = blockIdx.x & 7;
  const int b = combo & 1, chunk = combo >> 1;
  const int q0 = (blockIdx.x >> 3) * 16;
  const int k0 = chunk * 512;
  const float c = 0.03125f * 1.44269504f;  // (1/sqrt(E)) * log2(e), E=1024
  const long bh16 = (long)(b * 16);

  f32x4 ctx[4][4] = {};

  // per-(b,h) fragment stride = 131072 elems
  const __hip_bfloat16* Qt = Qf + bh16 * 131072 + (long)(q0 >> 4) * 1024 + lane * 8;
  const __hip_bfloat16* Kb0 = Kf + bh16 * 131072 + lane * 8;
  const __hip_bfloat16* Vb0 = Vf + bh16 * 131072 + lane * 8;

  for (int kk = k0; kk < k0 + 512; kk += 64) {
    const __hip_bfloat16* Kt = Kb0 + (long)((kk >> 4) + wv) * 1024;
    f32x4 s[16];
    // 4 groups of 4 heads: 8 coalesced K-frags (32 VGPRs) in flight per group
#pragma unroll
    for (int g = 0; g < 4; ++g) {
      bf16x8 kfa[4], kfb[4];
#pragma unroll
      for (int hh = 0; hh < 4; ++hh) {
        const __hip_bfloat16* kp = Kt + (long)(g * 4 + hh) * 131072;
        kfa[hh] = *(const bf16x8*)kp;
        kfb[hh] = *(const bf16x8*)(kp + 512);
      }
#pragma unroll
      for (int hh = 0; hh < 4; ++hh) {
        const int h = g * 4 + hh;
        const __hip_bfloat16* qp = Qt + (long)h * 131072;
        bf16x8 qa = *(const bf16x8*)qp;
        bf16x8 qb = *(const bf16x8*)(qp + 512);
        f32x4 a = {};
        a = MFMA16(qa, kfa[hh], a);
        a = MFMA16(qb, kfb[hh], a);
        s[h] = a;
      }
    }
    // head-axis softmax per lane (no max-sub: |score| small at scale 1/32)
    f32x4 sum = {0.f, 0.f, 0.f, 0.f};
#pragma unroll
    for (int h = 0; h < 16; ++h) {
#pragma unroll
      for (int r = 0; r < 4; ++r) s[h][r] = __builtin_amdgcn_exp2f(s[h][r] * c);
      sum += s[h];
    }
    f32x4 inv;
#pragma unroll
    for (int r = 0; r < 4; ++r) inv[r] = __builtin_amdgcn_rcpf(sum[r]);
    // P[h*16+q][k] swizzled; this wave's k-columns = wv*16 + lr
    const int gcol = (wv * 16 + lr) >> 3, coff = lr & 7;
#pragma unroll
    for (int h = 0; h < 16; ++h)
#pragma unroll
      for (int r = 0; r < 4; ++r) {
        int row = h * 16 + lq * 4 + r;
        P[row * 64 + ((gcol ^ (row & 7)) << 3) + coff] = __float2bfloat16(s[h][r] * inv[r]);
      }
    __syncthreads();
    // ---- PV for this wave's 4 heads; V frags coalesced, batched per head ----
#pragma unroll
    for (int hh = 0; hh < 4; ++hh) {
      const int h = wv * 4 + hh;
      const __hip_bfloat16* vb = Vb0 + (long)h * 131072 + (long)(kk >> 5) * 2048;
      bf16x8 vf[8];
#pragma unroll
      for (int ks = 0; ks < 2; ++ks)
#pragma unroll
        for (int dt = 0; dt < 4; ++dt)
          vf[ks * 4 + dt] = *(const bf16x8*)(vb + ks * 2048 + dt * 512);
      const int prow = h * 16 + lr;
      bf16x8 pf0 = *(const bf16x8*)&P[prow * 64 + ((lq ^ (lr & 7)) << 3)];
      bf16x8 pf1 = *(const bf16x8*)&P[prow * 64 + (((lq + 4) ^ (lr & 7)) << 3)];
#pragma unroll
      for (int dt = 0; dt < 4; ++dt) {
        ctx[hh][dt] = MFMA16(pf0, vf[dt], ctx[hh][dt]);
        ctx[hh][dt] = MFMA16(pf1, vf[4 + dt], ctx[hh][dt]);
      }
    }
    __syncthreads();
  }

  // ---- epilogue: ctx -> LDS (reuse P, same swizzle) -> coalesced wide store ----
  unsigned short* Pc = (unsigned short*)P;
#pragma unroll
  for (int hh = 0; hh < 4; ++hh) {
    int h = wv * 4 + hh;
#pragma unroll
    for (int dt = 0; dt < 4; ++dt) {
      int g = dt * 2 + (lr >> 3), off = lr & 7;
#pragma unroll
      for (int r = 0; r < 4; ++r) {
        int row = h * 16 + lq * 4 + r;
        Pc[row * 64 + ((g ^ (row & 7)) << 3) + off] = bf16bits(ctx[hh][dt][r]);
      }
    }
  }
  __syncthreads();
  // part[chunk][b][q0..q0+15][h*64+d]: contiguous 32 KB per CTA.
  unsigned short* gbase = (unsigned short*)part + ((long)(chunk * 4096 + b * 2048 + q0)) * 1024;
#pragma unroll
  for (int j = 0; j < 8; ++j) {
    int gf = (j * 256 + t) * 8;            // flat over [16q][16h][64d]
    int q = gf >> 10, hd = gf & 1023;
    int h = hd >> 6, d = hd & 63;
    int row = h * 16 + q, gd = (d >> 3) & 7;
    u16x8 v = *(const u16x8*)&Pc[row * 64 + ((gd ^ (row & 7)) << 3)];
    *(u16x8*)&gbase[gf] = v;
  }
}

// ---------------- reduce 4 bf16 chunk partials + cast to bf16 ----------------
__global__ void reduce_cast_kernel(const unsigned short* __restrict__ part,
                                   __hip_bfloat16* __restrict__ dst) {
  int i = blockIdx.x * blockDim.x + threadIdx.x;  // 1M threads, 4 elems each
  const long S4 = (long)4096 * 1024 / 4;          // ushort4 units per chunk
  const ushort4* p = (const ushort4*)part;
  float sx = 0.f, sy = 0.f, sz = 0.f, sw = 0.f;
#pragma unroll
  for (int c = 0; c < 4; ++c) {
    ushort4 v = p[i + c * S4];
    sx += bf2f(v.x); sy += bf2f(v.y); sz += bf2f(v.z); sw += bf2f(v.w);
  }
  ushort4 u;
  u.x = bf16bits(sx); u.y = bf16bits(sy); u.z = bf16bits(sz); u.w = bf16bits(sw);
  ((ushort4*)dst)[i] = u;
}

// ---------------- GEMM2: out = ctxb @ woutb^T + b_out (fp32 out) ----------------
__global__ __launch_bounds__(256) void gemm_out_kernel(
    const __hip_bfloat16* __restrict__ A,   // [4096][1024]
    const __hip_bfloat16* __restrict__ B,   // [1024][1024]
    const float* __restrict__ bias,
    float* __restrict__ out) {
  const int K = 1024;
  __shared__ __align__(16) __hip_bfloat16 As[128 * 32];
  __shared__ __align__(16) __hip_bfloat16 Bs[128 * 32];
  const int t = threadIdx.x;
  const int lane = t & 63, wv = t >> 6;
  const int wm = (wv >> 1) * 64, wn = (wv & 1) * 64;
  const int lr = lane & 15, lq = lane >> 4;
  const int m0 = blockIdx.y * 128, n0 = blockIdx.x * 128;

  f32x4 acc[4][4] = {};

  const int arow = t >> 2;
  const int acol = (t & 3) * 8;
  const __hip_bfloat16* Ag = A + (long)(m0 + arow) * K + acol;
  const __hip_bfloat16* Bg = B + (long)(n0 + arow) * K + acol;
  __hip_bfloat16* Asl = As + t * 8;
  __hip_bfloat16* Bsl = Bs + t * 8;

  for (int kk = 0; kk < K; kk += 32) {
    gload16(Ag + kk, Asl);
    gload16(Ag + kk + 64 * K, Asl + 2048);
    gload16(Bg + kk, Bsl);
    gload16(Bg + kk + 64 * K, Bsl + 2048);
    __syncthreads();
    bf16x8 af[4], bf[4];
#pragma unroll
    for (int i = 0; i < 4; ++i)
      af[i] = *(const bf16x8*)&As[(wm + i * 16 + lr) * 32 + lq * 8];
#pragma unroll
    for (int j = 0; j < 4; ++j)
      bf[j] = *(const bf16x8*)&Bs[(wn + j * 16 + lr) * 32 + lq * 8];
#pragma unroll
    for (int i = 0; i < 4; ++i)
#pragma unroll
      for (int j = 0; j < 4; ++j)
        acc[i][j] = MFMA16(af[i], bf[j], acc[i][j]);
    __syncthreads();
  }

#pragma unroll
  for (int i = 0; i < 4; ++i) {
#pragma unroll
    for (int j = 0; j < 4; ++j) {
      int col = n0 + wn + j * 16 + lr;
      float bs = bias[col];
      int rowb = m0 + wm + i * 16 + lq * 4;
#pragma unroll
      for (int r = 0; r < 4; ++r) {
        out[(long)(rowb + r) * 1024 + col] = acc[i][j][r] + bs;
      }
    }
  }
}

extern "C" void kernel_launch(void* const* d_in, const int* in_sizes, int n_in,
                              void* d_out, int out_size, void* d_ws, size_t ws_size,
                              hipStream_t stream) {
  const float* x     = (const float*)d_in[0];
  const float* w_qkv = (const float*)d_in[1];
  const float* b_qkv = (const float*)d_in[2];
  const float* w_out = (const float*)d_in[3];
  const float* b_out = (const float*)d_in[4];
  float* out = (float*)d_out;
  char* ws = (char*)d_ws;

  // workspace layout (80 MB total)
  __hip_bfloat16* xb    = (__hip_bfloat16*)(ws);                       // 8 MB
  __hip_bfloat16* wqkvb = (__hip_bfloat16*)(ws + (8ul << 20));         // 6 MB
  __hip_bfloat16* woutb = (__hip_bfloat16*)(ws + (14ul << 20));        // 2 MB
  __hip_bfloat16* Qfb   = (__hip_bfloat16*)(ws + (16ul << 20));        // 8 MB (fragment order)
  __hip_bfloat16* Kfb   = (__hip_bfloat16*)(ws + (24ul << 20));        // 8 MB (fragment order)
  __hip_bfloat16* Vfb   = (__hip_bfloat16*)(ws + (32ul << 20));        // 8 MB (fragment order)
  __hip_bfloat16* partb = (__hip_bfloat16*)(ws + (40ul << 20));        // 32 MB (4 bf16 chunks)
  __hip_bfloat16* ctxb  = (__hip_bfloat16*)(ws + (72ul << 20));        // 8 MB

  cast_kernel<<<4096, 256, 0, stream>>>(x, xb, 4194304 / 4);
  cast_kernel<<<3072, 256, 0, stream>>>(w_qkv, wqkvb, 3145728 / 4);
  cast_kernel<<<1024, 256, 0, stream>>>(w_out, woutb, 1048576 / 4);
  gemm_qkv_kernel<<<dim3(24, 32), 256, 0, stream>>>(xb, wqkvb, b_qkv, Qfb, Kfb, Vfb);
  attn_kernel<<<1024, 256, 0, stream>>>(Qfb, Kfb, Vfb, partb);
  reduce_cast_kernel<<<4096, 256, 0, stream>>>((const unsigned short*)partb, ctxb);
  gemm_out_kernel<<<dim3(8, 32), 256, 0, stream>>>(ctxb, woutb, b_out, out);
}